// Round 9
// baseline (258.206 us; speedup 1.0000x reference)
//
#include <hip/hip_runtime.h>

// Lowpass IIR scan: level[t] = (1-s)*x[t] + s*level[t-1], s = sigmoid(smooth).
// SINGLE-DISPATCH chunked scan, sync v4 (cache-bypass, zero wbl2/inv) + v5:
//   - C=64 chunks -> 1024 blocks = 4 blocks/CU (16 waves/CU), all co-resident
//     (launch_bounds(256,4), VGPR<=128). R8 showed occupancy was GRID-limited
//     (2 blocks/CU lockstep phases -> 2.86 TB/s). More blocks = read/write
//     stream overlap per CU + smoother tail.
//   - per-batch completion mask is ONE 64-bit word (bit c), relaxed atomics.
//   - P publish/lookback packed as 8-byte relaxed cache-bypass atomics.
// History: R3 392us (acquire storm) -> R6 205 (1 poller) -> R7 199 (padding
// null) -> R8 98us (cache-bypass sync; FETCH 132MB = input read once, proven).
// Ordering: __syncthreads drains vmcnt (P stores acked) before tid0 sets the
// flag; consumer polls flag, __syncthreads, then bypass-loads P (never cached
// -> no staleness). No threadfence anywhere.

typedef float f32x4 __attribute__((ext_vector_type(4)));

constexpr int B   = 16;
constexpr int T   = 2048;
constexpr int U   = 1024;
constexpr int U4  = U / 4;        // 256 float4 per row
constexpr int BU4 = B * U4;       // 4096 chain-groups
constexpr int FLAG_STRIDE_ULL = 16;   // 64-bit words per batch slot (128 B)

union f2u { float f[2]; unsigned long long u; };

__device__ __forceinline__ float sigmoidf(float x) {
    return 1.0f / (1.0f + __expf(-x));
}

// ======================= fused single-dispatch =======================
template <int C>
__global__ __launch_bounds__(256, 4) void lowpass_fused(
    const f32x4* __restrict__ in,      // [B*T*U4]
    const float* __restrict__ level0,  // [U]
    const float* __restrict__ smooth,  // [U]
    unsigned long long* __restrict__ Pq,   // [C*BU4*2] 8B words (bypass)
    unsigned long long* __restrict__ mask, // [B*FLAG_STRIDE_ULL], zeroed
    f32x4*       __restrict__ out)     // [B*T*U4]
{
    constexpr int L  = T / C;
    constexpr int DA = 16;
    constexpr int DB = 8;
    constexpr int LOG2L = 31 - __builtin_clz(L);
    static_assert(L > DA && L % DA == 0, "A prefetch");
    static_assert(L > DB && L % DB == 0, "B prefetch");
    static_assert((1 << LOG2L) == L, "pow2");
    static_assert(C <= 64, "mask fits u64");

    const int c   = (int)blockIdx.x >> 4;   // chunk (low blockIdx = low c)
    const int b   = (int)blockIdx.x & 15;   // batch
    const int tid = (int)threadIdx.x;       // float4 column 0..255
    const int lg  = b * U4 + tid;
    unsigned long long* const flag = &mask[b * FLAG_STRIDE_ULL];

    const f32x4 sm = reinterpret_cast<const f32x4*>(smooth)[tid];
    const float s0 = sigmoidf(sm.x), s1 = sigmoidf(sm.y),
                s2 = sigmoidf(sm.z), s3 = sigmoidf(sm.w);
    const float o0 = 1.0f - s0, o1 = 1.0f - s1,
                o2 = 1.0f - s2, o3 = 1.0f - s3;

    const int base = (b * T + c * L) * U4 + tid;
    const f32x4* __restrict__ ip = in + base;

    // ---------------- Phase A: chunk partial (zero entry) ----------------
    float a0 = 0.0f, a1 = 0.0f, a2 = 0.0f, a3 = 0.0f;
    {
        f32x4 buf[DA];
        #pragma unroll
        for (int i = 0; i < DA; ++i) buf[i] = ip[i * U4];

        int t = 0;
        for (; t < L - DA; t += DA) {
            #pragma unroll
            for (int j = 0; j < DA; ++j) {
                f32x4 x = buf[j];
                buf[j] = ip[(t + DA + j) * U4];
                a0 = fmaf(s0, a0, o0 * x.x);
                a1 = fmaf(s1, a1, o1 * x.y);
                a2 = fmaf(s2, a2, o2 * x.z);
                a3 = fmaf(s3, a3, o3 * x.w);
            }
        }
        #pragma unroll
        for (int j = 0; j < DA; ++j) {
            f32x4 x = buf[j];
            a0 = fmaf(s0, a0, o0 * x.x);
            a1 = fmaf(s1, a1, o1 * x.y);
            a2 = fmaf(s2, a2, o2 * x.z);
            a3 = fmaf(s3, a3, o3 * x.w);
        }
    }
    // publish partial via cache-bypass 8B stores (no threadfence, no wbl2)
    {
        f2u lo, hi;
        lo.f[0] = a0; lo.f[1] = a1; hi.f[0] = a2; hi.f[1] = a3;
        const size_t po = ((size_t)c * BU4 + lg) * 2;
        __hip_atomic_store(&Pq[po + 0], lo.u, __ATOMIC_RELAXED, __HIP_MEMORY_SCOPE_AGENT);
        __hip_atomic_store(&Pq[po + 1], hi.u, __ATOMIC_RELAXED, __HIP_MEMORY_SCOPE_AGENT);
    }

    // __syncthreads drains vmcnt -> all P stores memory-acked before flag
    __syncthreads();
    if (tid == 0) {
        __hip_atomic_fetch_or(flag, 1ull << c,
                              __ATOMIC_RELAXED, __HIP_MEMORY_SCOPE_AGENT);
        const unsigned long long need =
            (c == 0) ? 0ull : ((1ull << c) - 1ull);
        if (need) {
            while ((__hip_atomic_load(flag, __ATOMIC_RELAXED,
                                      __HIP_MEMORY_SCOPE_AGENT) & need) != need) {
                __builtin_amdgcn_s_sleep(32);   // ~1us between polls
            }
        }
    }
    __syncthreads();                 // compiler+HW fence; block proceeds

    // ---------------- entry level: Horner over preceding partials --------
    float sL0 = s0, sL1 = s1, sL2 = s2, sL3 = s3;
    #pragma unroll
    for (int i = 0; i < LOG2L; ++i) {
        sL0 *= sL0; sL1 *= sL1; sL2 *= sL2; sL3 *= sL3;
    }
    const f32x4 l0 = reinterpret_cast<const f32x4*>(level0)[tid];
    float v0 = l0.x, v1 = l0.y, v2 = l0.z, v3 = l0.w;
    for (int i = 0; i < c; ++i) {
        // cache-bypass loads (L3-served; never cached -> no staleness)
        const size_t po = ((size_t)i * BU4 + lg) * 2;
        f2u lo, hi;
        lo.u = __hip_atomic_load(&Pq[po + 0], __ATOMIC_RELAXED, __HIP_MEMORY_SCOPE_AGENT);
        hi.u = __hip_atomic_load(&Pq[po + 1], __ATOMIC_RELAXED, __HIP_MEMORY_SCOPE_AGENT);
        v0 = fmaf(sL0, v0, lo.f[0]);
        v1 = fmaf(sL1, v1, lo.f[1]);
        v2 = fmaf(sL2, v2, hi.f[0]);
        v3 = fmaf(sL3, v3, hi.f[1]);
    }

    // ---------------- Phase B: scan + store (input L3-warm) --------------
    f32x4* __restrict__ op = out + base;
    f32x4 buf[DB];
    #pragma unroll
    for (int i = 0; i < DB; ++i) buf[i] = ip[i * U4];

    int t = 0;
    for (; t < L - DB; t += DB) {
        #pragma unroll
        for (int j = 0; j < DB; ++j) {
            f32x4 x = buf[j];
            buf[j] = ip[(t + DB + j) * U4];
            v0 = fmaf(s0, v0, o0 * x.x);
            v1 = fmaf(s1, v1, o1 * x.y);
            v2 = fmaf(s2, v2, o2 * x.z);
            v3 = fmaf(s3, v3, o3 * x.w);
            f32x4 r; r.x = v0; r.y = v1; r.z = v2; r.w = v3;
            __builtin_nontemporal_store(r, &op[(t + j) * U4]);
        }
    }
    #pragma unroll
    for (int j = 0; j < DB; ++j) {
        f32x4 x = buf[j];
        v0 = fmaf(s0, v0, o0 * x.x);
        v1 = fmaf(s1, v1, o1 * x.y);
        v2 = fmaf(s2, v2, o2 * x.z);
        v3 = fmaf(s3, v3, o3 * x.w);
        f32x4 r; r.x = v0; r.y = v1; r.z = v2; r.w = v3;
        __builtin_nontemporal_store(r, &op[(t + j) * U4]);
    }
}

// ============== fallback: proven two-kernel version (R4) ==============
template <int C>
__global__ __launch_bounds__(256, 2) void lowpass_partial(
    const f32x4* __restrict__ in, const float* __restrict__ smooth,
    f32x4* __restrict__ P)
{
    constexpr int L  = T / C;
    constexpr int DA = 16;
    const int c   = (int)blockIdx.x >> 4;
    const int b   = (int)blockIdx.x & 15;
    const int tid = (int)threadIdx.x;
    const int lg  = b * U4 + tid;

    const f32x4 sm = reinterpret_cast<const f32x4*>(smooth)[tid];
    const float s0 = sigmoidf(sm.x), s1 = sigmoidf(sm.y),
                s2 = sigmoidf(sm.z), s3 = sigmoidf(sm.w);
    const float o0 = 1.0f - s0, o1 = 1.0f - s1,
                o2 = 1.0f - s2, o3 = 1.0f - s3;

    const f32x4* __restrict__ ip = in + (b * T + c * L) * U4 + tid;
    float a0 = 0, a1 = 0, a2 = 0, a3 = 0;
    f32x4 buf[DA];
    #pragma unroll
    for (int i = 0; i < DA; ++i) buf[i] = ip[i * U4];
    int t = 0;
    for (; t < L - DA; t += DA) {
        #pragma unroll
        for (int j = 0; j < DA; ++j) {
            f32x4 x = buf[j];
            buf[j] = ip[(t + DA + j) * U4];
            a0 = fmaf(s0, a0, o0 * x.x); a1 = fmaf(s1, a1, o1 * x.y);
            a2 = fmaf(s2, a2, o2 * x.z); a3 = fmaf(s3, a3, o3 * x.w);
        }
    }
    #pragma unroll
    for (int j = 0; j < DA; ++j) {
        f32x4 x = buf[j];
        a0 = fmaf(s0, a0, o0 * x.x); a1 = fmaf(s1, a1, o1 * x.y);
        a2 = fmaf(s2, a2, o2 * x.z); a3 = fmaf(s3, a3, o3 * x.w);
    }
    f32x4 part; part.x = a0; part.y = a1; part.z = a2; part.w = a3;
    P[c * BU4 + lg] = part;
}

template <int C>
__global__ __launch_bounds__(256, 2) void lowpass_scan(
    const f32x4* __restrict__ in, const float* __restrict__ level0,
    const float* __restrict__ smooth, const f32x4* __restrict__ P,
    f32x4* __restrict__ out)
{
    constexpr int L  = T / C;
    constexpr int DB = 8;
    constexpr int LOG2L = 31 - __builtin_clz(L);
    const int c   = (int)blockIdx.x >> 4;
    const int b   = (int)blockIdx.x & 15;
    const int tid = (int)threadIdx.x;
    const int lg  = b * U4 + tid;

    const f32x4 sm = reinterpret_cast<const f32x4*>(smooth)[tid];
    const float s0 = sigmoidf(sm.x), s1 = sigmoidf(sm.y),
                s2 = sigmoidf(sm.z), s3 = sigmoidf(sm.w);
    const float o0 = 1.0f - s0, o1 = 1.0f - s1,
                o2 = 1.0f - s2, o3 = 1.0f - s3;

    float sL0 = s0, sL1 = s1, sL2 = s2, sL3 = s3;
    #pragma unroll
    for (int i = 0; i < LOG2L; ++i) { sL0*=sL0; sL1*=sL1; sL2*=sL2; sL3*=sL3; }

    const f32x4 l0 = reinterpret_cast<const f32x4*>(level0)[tid];
    float v0 = l0.x, v1 = l0.y, v2 = l0.z, v3 = l0.w;
    for (int i = 0; i < c; ++i) {
        f32x4 p = P[i * BU4 + lg];
        v0 = fmaf(sL0, v0, p.x); v1 = fmaf(sL1, v1, p.y);
        v2 = fmaf(sL2, v2, p.z); v3 = fmaf(sL3, v3, p.w);
    }

    const int base = (b * T + c * L) * U4 + tid;
    const f32x4* __restrict__ ip = in + base;
    f32x4* __restrict__ op = out + base;
    f32x4 buf[DB];
    #pragma unroll
    for (int i = 0; i < DB; ++i) buf[i] = ip[i * U4];
    int t = 0;
    for (; t < L - DB; t += DB) {
        #pragma unroll
        for (int j = 0; j < DB; ++j) {
            f32x4 x = buf[j];
            buf[j] = ip[(t + DB + j) * U4];
            v0 = fmaf(s0, v0, o0 * x.x); v1 = fmaf(s1, v1, o1 * x.y);
            v2 = fmaf(s2, v2, o2 * x.z); v3 = fmaf(s3, v3, o3 * x.w);
            f32x4 r; r.x = v0; r.y = v1; r.z = v2; r.w = v3;
            __builtin_nontemporal_store(r, &op[(t + j) * U4]);
        }
    }
    #pragma unroll
    for (int j = 0; j < DB; ++j) {
        f32x4 x = buf[j];
        v0 = fmaf(s0, v0, o0 * x.x); v1 = fmaf(s1, v1, o1 * x.y);
        v2 = fmaf(s2, v2, o2 * x.z); v3 = fmaf(s3, v3, o3 * x.w);
        f32x4 r; r.x = v0; r.y = v1; r.z = v2; r.w = v3;
        __builtin_nontemporal_store(r, &op[(t + j) * U4]);
    }
}

extern "C" void kernel_launch(void* const* d_in, const int* in_sizes, int n_in,
                              void* d_out, int out_size, void* d_ws, size_t ws_size,
                              hipStream_t stream) {
    const f32x4* in     = (const f32x4*)d_in[0];  // inputs [B,T,U]
    const float* level0 = (const float*)d_in[1];  // level_var [1,U]
    const float* smooth = (const float*)d_in[2];  // smoothing_var [1,U]
    f32x4* out          = (f32x4*)d_out;

    const size_t fBytes = (size_t)B * FLAG_STRIDE_ULL * sizeof(unsigned long long); // 2 KiB
    const size_t p64 = (size_t)64 * BU4 * 16;   // 4 MiB
    const size_t p32 = (size_t)32 * BU4 * 16;   // 2 MiB (proven available)

    if (ws_size >= p64 + fBytes) {
        constexpr int C = 64;
        unsigned long long* Pq   = (unsigned long long*)d_ws;
        unsigned long long* mask = (unsigned long long*)((char*)d_ws + p64);
        (void)hipMemsetAsync(mask, 0, fBytes, stream);
        hipLaunchKernelGGL(lowpass_fused<C>, dim3(C * B), dim3(256), 0, stream,
                           in, level0, smooth, Pq, mask, out);
    } else if (ws_size >= p32 + fBytes) {
        constexpr int C = 32;
        unsigned long long* Pq   = (unsigned long long*)d_ws;
        unsigned long long* mask = (unsigned long long*)((char*)d_ws + p32);
        (void)hipMemsetAsync(mask, 0, fBytes, stream);
        hipLaunchKernelGGL(lowpass_fused<C>, dim3(C * B), dim3(256), 0, stream,
                           in, level0, smooth, Pq, mask, out);
    } else {                                                  // 512 KiB fallback
        constexpr int C = 8;
        f32x4* P = (f32x4*)d_ws;
        dim3 grid(C * B);
        hipLaunchKernelGGL(lowpass_partial<C>, grid, dim3(256), 0, stream,
                           in, smooth, P);
        hipLaunchKernelGGL(lowpass_scan<C>,    grid, dim3(256), 0, stream,
                           in, level0, smooth, P, out);
    }
}